// Round 15
// baseline (238.057 us; speedup 1.0000x reference)
//
#include <hip/hip_runtime.h>
#include <hip/hip_bf16.h>

typedef float f32x4 __attribute__((ext_vector_type(4)));
typedef short bf16x8 __attribute__((ext_vector_type(8)));

#define BCAP 20480   // per-bucket capacity (mean 17408, +24 sigma)

__device__ __forceinline__ float4 ld4(const float* p){ return *reinterpret_cast<const float4*>(p); }
__device__ __forceinline__ unsigned short f2bf(float f){
  unsigned int u = __float_as_uint(f);
  u = (u + 0x7fffu + ((u>>16)&1u)) >> 16;
  return (unsigned short)u;
}
__device__ __forceinline__ float bflo(unsigned int u){ return __uint_as_float(u<<16); }
__device__ __forceinline__ float bfhi(unsigned int u){ return __uint_as_float(u & 0xffff0000u); }
__device__ __forceinline__ float bfs(short s){ return __uint_as_float(((unsigned)(unsigned short)s)<<16); }
__device__ __forceinline__ float ftanh(float x){
  float e = __expf(2.f*x);
  return fmaf(-2.f, __builtin_amdgcn_rcpf(e+1.f), 1.f);
}

// =============== fused: weight prep (blocks 0..4) | edge bucketing (blocks 5+) ===============
__global__ __launch_bounds__(256) void k_prep_bucket(
    const float* __restrict__ W0, const float* __restrict__ W12, const float* __restrict__ Watt,
    const float* __restrict__ as0, const float* __restrict__ ad0,
    const float* __restrict__ as12, const float* __restrict__ ad12,
    const float* __restrict__ Wout, unsigned short* __restrict__ dst,
    const int* __restrict__ ei, int* __restrict__ bcnt, unsigned* __restrict__ bdata,
    int E_, int Et)
{
  __shared__ char smraw[32768];
  int b = blockIdx.x, t = threadIdx.x;
  if (b < 5){
    // ---------------- prep ----------------
    if (b == 4){
      unsigned short* wo = dst + (size_t)4*18432;
      for (int i=t; i<48*128; i+=256){
        int col = i>>7, k = i&127;
        float v = (col < 40) ? Wout[(size_t)k*40 + col] : 0.f;
        unsigned short hi = f2bf(v);
        float r = v - __uint_as_float(((unsigned)hi)<<16);
        wo[i] = hi;
        wo[48*128 + i] = f2bf(r);
      }
      return;
    }
    float* Wf = (float*)smraw;
    const float* W = (b==0) ? W0 : (b==3 ? Watt : W12 + (size_t)(b-1)*16384);
    unsigned short* out = dst + (size_t)b*18432;
    const float* as_ = (b==0) ? as0 : as12 + (size_t)(b-1)*128;
    const float* ad_ = (b==0) ? ad0 : ad12 + (size_t)(b-1)*128;

    for (int half=0; half<2; half++){
      #pragma unroll
      for (int p=0;p<8;p++){
        int i = p*256 + t;
        *reinterpret_cast<float4*>(&Wf[i*4]) = ld4(&W[(size_t)half*8192 + i*4]);
      }
      __syncthreads();
      {
        int col = t>>1, koff = (t&1)*32;
        #pragma unroll
        for (int j=0;j<4;j++){
          unsigned short tmp[8];
          #pragma unroll
          for (int q=0;q<8;q++) tmp[q] = f2bf(Wf[(koff + j*8 + q)*128 + col]);
          *reinterpret_cast<uint4*>(&out[col*128 + half*64 + koff + j*8]) = *reinterpret_cast<const uint4*>(tmp);
        }
      }
      {
        int ce = t>>4;
        int h  = ce & 7;
        if (b < 3){
          const float* av = (ce < 8) ? (as_ + h*16) : (ad_ + h*16);
          float avr[16];
          #pragma unroll
          for (int c2=0;c2<16;c2++) avr[c2] = av[c2];
          #pragma unroll
          for (int i=0;i<4;i++){
            int kl = (t&15) + i*16;
            float s = 0.f;
            #pragma unroll
            for (int c2=0;c2<16;c2++) s += Wf[kl*128 + h*16 + c2]*avr[c2];
            out[(128+ce)*128 + half*64 + kl] = f2bf(s);
          }
        } else {
          #pragma unroll
          for (int i=0;i<4;i++){
            int kl = (t&15) + i*16;
            out[(128+ce)*128 + half*64 + kl] = 0;
          }
        }
      }
      __syncthreads();
    }
    return;
  }
  // ---------------- bucket ----------------
  int* h    = (int*)smraw;
  int* base = (int*)(smraw + 256);
  if (t < 64) h[t] = 0;
  __syncthreads();
  int e0 = (b-5)*2048 + t;
  int dv[8], sv[8], rv[8];
  #pragma unroll
  for (int k=0;k<8;k++){
    int e = e0 + k*256;
    if (e < Et){
      int s, d;
      if (e < E_){ s = ei[e]; d = ei[E_+e]; } else { s = e-E_; d = s; }
      dv[k] = d; sv[k] = s;
      rv[k] = atomicAdd(&h[d>>10], 1);
    } else dv[k] = -1;
  }
  __syncthreads();
  if (t < 64 && h[t]) base[t] = atomicAdd(&bcnt[t], h[t]);
  __syncthreads();
  #pragma unroll
  for (int k=0;k<8;k++){
    if (dv[k] >= 0){
      int bk = dv[k]>>10;
      bdata[(size_t)bk*BCAP + base[bk] + rv[k]] = ((unsigned)(dv[k]&1023)<<17) | (unsigned)sv[k];
    }
  }
}

// =============== fused: CSR finish (blocks 0..nb-1) | layer-0 GEMM fp32-A (blocks nb+) ===============
__global__ __launch_bounds__(512) void k_bfinish_gemm0(
    const unsigned* __restrict__ bdata, const int* __restrict__ bcnt,
    int* __restrict__ off, int* __restrict__ csr, int N_, int nb,
    const float* __restrict__ x, const unsigned short* __restrict__ Bt,
    unsigned short* __restrict__ C, float* __restrict__ s_src, float* __restrict__ s_dst)
{
  __shared__ int c[1024];
  __shared__ int wsum[8];
  __shared__ int bbase_s;
  int t = threadIdx.x;
  if ((int)blockIdx.x < nb){
    int b = blockIdx.x;
    if (t < 64){
      int v = (t < nb) ? bcnt[t] : 0;
      int incl = v;
      #pragma unroll
      for (int d=1; d<64; d<<=1){ int u = __shfl_up(incl, d); if (t>=d) incl += u; }
      if (t == b) bbase_s = incl - v;
      if (b == 0 && t == 63) off[N_] = incl;
    }
    int cnt = bcnt[b];
    size_t lo = (size_t)b*BCAP;
    for (int i=t;i<1024;i+=512) c[i]=0;
    __syncthreads();
    for (int i=t; i<cnt; i+=512) atomicAdd(&c[bdata[lo+i]>>17], 1);
    __syncthreads();
    int c0 = c[2*t], c1 = c[2*t+1];
    int s = c0 + c1;
    int lane = t&63, w = t>>6;
    int incl = s;
    #pragma unroll
    for (int d=1; d<64; d<<=1){ int u = __shfl_up(incl, d); if (lane>=d) incl += u; }
    if (lane==63) wsum[w] = incl;
    __syncthreads();
    int wpre = 0;
    #pragma unroll
    for (int k=0;k<8;k++) if (k<w) wpre += wsum[k];
    int run = bbase_s + wpre + incl - s;
    int n = (b<<10) + 2*t;
    if (n   < N_) off[n]   = run;
    if (n+1 < N_) off[n+1] = run + c0;
    c[2*t]   = run;
    c[2*t+1] = run + c0;
    __syncthreads();
    for (int i=t; i<cnt; i+=512){
      unsigned p = bdata[lo+i];
      int pos = atomicAdd(&c[p>>17], 1);
      csr[pos] = (int)(p & 0x1FFFFu);
    }
    return;
  }
  // ---------------- gemm layer 0 (A = x, fp32) ----------------
  if (t >= 256) return;
  int lane = t & 63, w = t >> 6;
  int rA = lane & 15, g = lane >> 4;
  int r0 = (blockIdx.x - nb)*128 + w*32;
  f32x4 z = {0.f,0.f,0.f,0.f};
  f32x4 acc[2][9];
  #pragma unroll
  for (int mf=0;mf<2;mf++)
    #pragma unroll
    for (int nf=0;nf<9;nf++) acc[mf][nf] = z;

  int M = N_;
  int rowc0 = min(r0 + rA,      M-1);
  int rowc1 = min(r0 + 16 + rA, M-1);
  #pragma unroll
  for (int ks=0; ks<4; ks++){
    int ko = ks*32 + g*8;
    bf16x8 a0, a1;
    float4 v0 = ld4(&x[(size_t)rowc0*128 + ko]);
    float4 v1 = ld4(&x[(size_t)rowc0*128 + ko + 4]);
    float4 v2 = ld4(&x[(size_t)rowc1*128 + ko]);
    float4 v3 = ld4(&x[(size_t)rowc1*128 + ko + 4]);
    a0[0]=(short)f2bf(v0.x); a0[1]=(short)f2bf(v0.y); a0[2]=(short)f2bf(v0.z); a0[3]=(short)f2bf(v0.w);
    a0[4]=(short)f2bf(v1.x); a0[5]=(short)f2bf(v1.y); a0[6]=(short)f2bf(v1.z); a0[7]=(short)f2bf(v1.w);
    a1[0]=(short)f2bf(v2.x); a1[1]=(short)f2bf(v2.y); a1[2]=(short)f2bf(v2.z); a1[3]=(short)f2bf(v2.w);
    a1[4]=(short)f2bf(v3.x); a1[5]=(short)f2bf(v3.y); a1[6]=(short)f2bf(v3.z); a1[7]=(short)f2bf(v3.w);
    #pragma unroll
    for (int nf=0;nf<9;nf++){
      bf16x8 bf_ = *reinterpret_cast<const bf16x8*>(Bt + (size_t)(nf*16+rA)*128 + ko);
      acc[0][nf] = __builtin_amdgcn_mfma_f32_16x16x32_bf16(a0, bf_, acc[0][nf], 0, 0, 0);
      acc[1][nf] = __builtin_amdgcn_mfma_f32_16x16x32_bf16(a1, bf_, acc[1][nf], 0, 0, 0);
    }
  }

  #pragma unroll
  for (int mf=0;mf<2;mf++){
    #pragma unroll
    for (int r=0;r<4;r++){
      int row = r0 + mf*16 + g*4 + r;
      if (row < M){
        #pragma unroll
        for (int nf=0;nf<8;nf++) C[(size_t)row*128 + nf*16 + rA] = f2bf(acc[mf][nf][r]);
        float sv_ = acc[mf][8][r];
        if (rA < 8) s_src[(size_t)row*8 + rA]     = sv_;
        else        s_dst[(size_t)row*8 + rA - 8] = sv_;
      }
    }
  }
}

// =============== MFMA GEMM (no LDS): A[M,128]bf16 @ Bt[144,128]bf16 (layers 1,2) ===============
__global__ __launch_bounds__(256) void k_gemm(
    const unsigned short* __restrict__ A, const unsigned short* __restrict__ Bt,
    unsigned short* __restrict__ C, float* __restrict__ s_src, float* __restrict__ s_dst, int M)
{
  int t = threadIdx.x, lane = t & 63, w = t >> 6;
  int rA = lane & 15, g = lane >> 4;
  int r0 = blockIdx.x*128 + w*32;
  f32x4 z = {0.f,0.f,0.f,0.f};
  f32x4 acc[2][9];
  #pragma unroll
  for (int mf=0;mf<2;mf++)
    #pragma unroll
    for (int nf=0;nf<9;nf++) acc[mf][nf] = z;

  int rowc0 = min(r0 + rA,      M-1);
  int rowc1 = min(r0 + 16 + rA, M-1);
  #pragma unroll
  for (int ks=0; ks<4; ks++){
    int ko = ks*32 + g*8;
    bf16x8 a0 = *reinterpret_cast<const bf16x8*>(A + (size_t)rowc0*128 + ko);
    bf16x8 a1 = *reinterpret_cast<const bf16x8*>(A + (size_t)rowc1*128 + ko);
    #pragma unroll
    for (int nf=0;nf<9;nf++){
      bf16x8 bf_ = *reinterpret_cast<const bf16x8*>(Bt + (size_t)(nf*16+rA)*128 + ko);
      acc[0][nf] = __builtin_amdgcn_mfma_f32_16x16x32_bf16(a0, bf_, acc[0][nf], 0, 0, 0);
      acc[1][nf] = __builtin_amdgcn_mfma_f32_16x16x32_bf16(a1, bf_, acc[1][nf], 0, 0, 0);
    }
  }

  #pragma unroll
  for (int mf=0;mf<2;mf++){
    #pragma unroll
    for (int r=0;r<4;r++){
      int row = r0 + mf*16 + g*4 + r;
      if (row < M){
        #pragma unroll
        for (int nf=0;nf<8;nf++) C[(size_t)row*128 + nf*16 + rA] = f2bf(acc[mf][nf][r]);
        float sv_ = acc[mf][8][r];
        if (rA < 8) s_src[(size_t)row*8 + rA]     = sv_;
        else        s_dst[(size_t)row*8 + rA - 8] = sv_;
      }
    }
  }
}

// =============== softmax-aggregate: channel-split by block parity ===============
// Block p=blockIdx&1 handles channels [p*64, p*64+64) (one 128B L2 line of each row)
// for 8 nodes. Consecutive blockIdx round-robin across XCDs -> each XCD touches only
// one line per htmp row (halves cross-XCD L2 replication). 32-lane half = 8 chunk
// lanes x 4 edge offsets -> 4 gathers in flight.
__global__ __launch_bounds__(256) void k_aggregate(
    const int* __restrict__ off, const int* __restrict__ csr,
    const unsigned short* __restrict__ htmp, const float* __restrict__ s_src,
    const float* __restrict__ s_dst, const float* __restrict__ bias,
    unsigned short* __restrict__ hout, int N_)
{
  __shared__ float esc[4][2][144];   // [wave][half][h*36 + e], e<32
  __shared__ int   ssrc[4][2][32];
  int t = threadIdx.x;
  int w = t >> 6;
  int lane = t & 63;
  int half = lane >> 5;      // node select within wave
  int l32  = lane & 31;
  int c8   = l32 & 7;        // 16B chunk within my 128B half-row
  int eo   = l32 >> 3;       // 0..3 edge offset
  int hl   = c8 >> 1;        // local head 0..3
  int p    = blockIdx.x & 1; // channel half
  int ng   = blockIdx.x >> 1;
  int n = ng*8 + w*2 + half;
  int base = 0, deg = 0;
  if (n < N_){ base = off[n]; deg = off[n+1] - base; }
  float sdv[4] = {0.f,0.f,0.f,0.f};
  if (n < N_){
    float4 sd = ld4(&s_dst[(size_t)n*8 + p*4]);
    sdv[0]=sd.x; sdv[1]=sd.y; sdv[2]=sd.z; sdv[3]=sd.w;
  }
  float acc0=0.f,acc1=0.f,acc2=0.f,acc3=0.f,acc4=0.f,acc5=0.f,acc6=0.f,acc7=0.f;
  float dsum = 0.f;
  const char* hb = (const char*)htmp + (p<<7) + (c8<<4);

  for (int cb=0; cb<deg; cb+=32){
    int cdeg = min(32, deg-cb);
    int srcj = 0;
    float ee[4];
    if (l32 < cdeg){
      srcj = csr[base+cb+l32];
      float4 a0 = ld4(&s_src[(size_t)srcj*8 + p*4]);
      float sv[4] = {a0.x,a0.y,a0.z,a0.w};
      #pragma unroll
      for (int h=0;h<4;h++){
        float v = sv[h] + sdv[h];
        v = v > 0.f ? v : 0.2f*v;
        ee[h] = __expf(v);
      }
    } else {
      #pragma unroll
      for (int h=0;h<4;h++) ee[h] = 0.f;
    }
    ssrc[w][half][l32] = srcj;
    #pragma unroll
    for (int h=0;h<4;h++) esc[w][half][h*36 + l32] = ee[h];
    asm volatile("s_waitcnt lgkmcnt(0)" ::: "memory");
    __builtin_amdgcn_sched_barrier(0);

    for (int j=0; j<cdeg; j+=8){
      int e0 = j + eo;
      int e1 = j + 4 + eo;
      int s0 = ssrc[w][half][e0];
      int s1 = ssrc[w][half][e1];
      float ev0 = esc[w][half][hl*36 + e0];
      float ev1 = esc[w][half][hl*36 + e1];
      uint4 u0 = *reinterpret_cast<const uint4*>(hb + ((size_t)(unsigned)s0<<8));
      uint4 u1 = *reinterpret_cast<const uint4*>(hb + ((size_t)(unsigned)s1<<8));
      acc0 = fmaf(ev0, bflo(u0.x), acc0);
      acc1 = fmaf(ev0, bfhi(u0.x), acc1);
      acc2 = fmaf(ev0, bflo(u0.y), acc2);
      acc3 = fmaf(ev0, bfhi(u0.y), acc3);
      acc4 = fmaf(ev0, bflo(u0.z), acc4);
      acc5 = fmaf(ev0, bfhi(u0.z), acc5);
      acc6 = fmaf(ev0, bflo(u0.w), acc6);
      acc7 = fmaf(ev0, bfhi(u0.w), acc7);
      acc0 = fmaf(ev1, bflo(u1.x), acc0);
      acc1 = fmaf(ev1, bfhi(u1.x), acc1);
      acc2 = fmaf(ev1, bflo(u1.y), acc2);
      acc3 = fmaf(ev1, bfhi(u1.y), acc3);
      acc4 = fmaf(ev1, bflo(u1.z), acc4);
      acc5 = fmaf(ev1, bfhi(u1.z), acc5);
      acc6 = fmaf(ev1, bflo(u1.w), acc6);
      acc7 = fmaf(ev1, bfhi(u1.w), acc7);
      dsum += ev0 + ev1;
    }
  }
  // merge the 4 edge-offset groups (xor 8 and 16 stay within the 32-lane half)
  acc0 += __shfl_xor(acc0, 8);  acc0 += __shfl_xor(acc0, 16);
  acc1 += __shfl_xor(acc1, 8);  acc1 += __shfl_xor(acc1, 16);
  acc2 += __shfl_xor(acc2, 8);  acc2 += __shfl_xor(acc2, 16);
  acc3 += __shfl_xor(acc3, 8);  acc3 += __shfl_xor(acc3, 16);
  acc4 += __shfl_xor(acc4, 8);  acc4 += __shfl_xor(acc4, 16);
  acc5 += __shfl_xor(acc5, 8);  acc5 += __shfl_xor(acc5, 16);
  acc6 += __shfl_xor(acc6, 8);  acc6 += __shfl_xor(acc6, 16);
  acc7 += __shfl_xor(acc7, 8);  acc7 += __shfl_xor(acc7, 16);
  dsum += __shfl_xor(dsum, 8);  dsum += __shfl_xor(dsum, 16);

  if (n < N_ && eo == 0){
    float inv = 1.f/(dsum + 1e-16f);
    int cbase = p*64 + c8*8;
    float4 b0 = ld4(&bias[cbase]);
    float4 b1 = ld4(&bias[cbase+4]);
    float o0 = fmaf(acc0, inv, b0.x);
    float o1 = fmaf(acc1, inv, b0.y);
    float o2 = fmaf(acc2, inv, b0.z);
    float o3 = fmaf(acc3, inv, b0.w);
    float o4 = fmaf(acc4, inv, b1.x);
    float o5 = fmaf(acc5, inv, b1.y);
    float o6 = fmaf(acc6, inv, b1.z);
    float o7 = fmaf(acc7, inv, b1.w);
    o0 = o0>0.f ? o0 : (__expf(o0)-1.f);
    o1 = o1>0.f ? o1 : (__expf(o1)-1.f);
    o2 = o2>0.f ? o2 : (__expf(o2)-1.f);
    o3 = o3>0.f ? o3 : (__expf(o3)-1.f);
    o4 = o4>0.f ? o4 : (__expf(o4)-1.f);
    o5 = o5>0.f ? o5 : (__expf(o5)-1.f);
    o6 = o6>0.f ? o6 : (__expf(o6)-1.f);
    o7 = o7>0.f ? o7 : (__expf(o7)-1.f);
    uint4 pk;
    pk.x = (unsigned)f2bf(o0) | ((unsigned)f2bf(o1)<<16);
    pk.y = (unsigned)f2bf(o2) | ((unsigned)f2bf(o3)<<16);
    pk.z = (unsigned)f2bf(o4) | ((unsigned)f2bf(o5)<<16);
    pk.w = (unsigned)f2bf(o6) | ((unsigned)f2bf(o7)<<16);
    *reinterpret_cast<uint4*>(&hout[(size_t)n*128 + cbase]) = pk;
  }
}

// =============== fused final v4: A-frag preload + B-share across layers ===============
// NOTE: no min-waves clamp ((256,4) caused 64-VGPR cap -> 134 MB spill, rounds 5/6).
__global__ __launch_bounds__(256) void k_final4(
    const unsigned short* __restrict__ h0, const unsigned short* __restrict__ h1,
    const unsigned short* __restrict__ h2,
    const unsigned short* __restrict__ WattT, const float* __restrict__ aatt,
    const unsigned short* __restrict__ WoutT,  // [48][128] hi, then [48][128] lo
    const float* __restrict__ bout, float* __restrict__ out, int M)
{
  int t = threadIdx.x, lane = t & 63, w = t >> 6;
  int rA = lane & 15, g = lane >> 4;
  int r0 = blockIdx.x*64 + w*16;
  int rowc = min(r0 + rA, M-1);

  float av[8];
  #pragma unroll
  for (int nf=0;nf<8;nf++) av[nf] = aatt[nf*16 + rA];

  bf16x8 a[3][4];
  #pragma unroll
  for (int ks=0;ks<4;ks++){
    int ko = ks*32 + g*8;
    a[0][ks] = *reinterpret_cast<const bf16x8*>(h0 + (size_t)rowc*128 + ko);
    a[1][ks] = *reinterpret_cast<const bf16x8*>(h1 + (size_t)rowc*128 + ko);
    a[2][ks] = *reinterpret_cast<const bf16x8*>(h2 + (size_t)rowc*128 + ko);
  }

  float sc[3][4];
  #pragma unroll
  for (int l=0;l<3;l++)
    #pragma unroll
    for (int r=0;r<4;r++) sc[l][r] = 0.f;

  #pragma unroll
  for (int ch=0; ch<4; ch++){
    f32x4 acc[3][2];
    #pragma unroll
    for (int l=0;l<3;l++){ acc[l][0] = (f32x4){0.f,0.f,0.f,0.f}; acc[l][1] = (f32x4){0.f,0.f,0.f,0.f}; }
    #pragma unroll
    for (int ks=0; ks<4; ks++){
      int ko = ks*32 + g*8;
      bf16x8 b0 = *reinterpret_cast<const bf16x8*>(WattT + (size_t)((ch*2+0)*16+rA)*128 + ko);
      bf16x8 b1 = *reinterpret_cast<const bf16x8*>(WattT + (size_t)((ch*2+1)*16+rA)*128 + ko);
      #pragma unroll
      for (int l=0;l<3;l++){
        acc[l][0] = __builtin_amdgcn_mfma_f32_16x16x32_bf16(a[l][ks], b0, acc[l][0], 0, 0, 0);
        acc[l][1] = __builtin_amdgcn_mfma_f32_16x16x32_bf16(a[l][ks], b1, acc[l][1], 0, 0, 0);
      }
    }
    float w0 = av[ch*2], w1 = av[ch*2+1];
    #pragma unroll
    for (int l=0;l<3;l++)
      #pragma unroll
      for (int r=0;r<4;r++)
        sc[l][r] += ftanh(acc[l][0][r])*w0 + ftanh(acc[l][1][r])*w1;
  }
  #pragma unroll
  for (int l=0;l<3;l++)
    #pragma unroll
    for (int r=0;r<4;r++){
      float s = sc[l][r];
      s += __shfl_xor(s, 1);
      s += __shfl_xor(s, 2);
      s += __shfl_xor(s, 4);
      s += __shfl_xor(s, 8);
      sc[l][r] = s;
    }

  float lam[3][4];
  #pragma unroll
  for (int r=0;r<4;r++){
    float m = fmaxf(sc[0][r], fmaxf(sc[1][r], sc[2][r]));
    float e0 = __expf(sc[0][r]-m), e1 = __expf(sc[1][r]-m), e2 = __expf(sc[2][r]-m);
    float inv = 1.f/(e0+e1+e2);
    lam[0][r]=e0*inv; lam[1][r]=e1*inv; lam[2][r]=e2*inv;
  }
  int rsel = rA & 3;
  int srcLane = ((rA>>2)<<4) | rA;
  float p0 = rsel==0 ? lam[0][0] : rsel==1 ? lam[0][1] : rsel==2 ? lam[0][2] : lam[0][3];
  float p1 = rsel==0 ? lam[1][0] : rsel==1 ? lam[1][1] : rsel==2 ? lam[1][2] : lam[1][3];
  float p2 = rsel==0 ? lam[2][0] : rsel==1 ? lam[2][1] : rsel==2 ? lam[2][2] : lam[2][3];
  float lamA[3];
  lamA[0] = __shfl(p0, srcLane);
  lamA[1] = __shfl(p1, srcLane);
  lamA[2] = __shfl(p2, srcLane);

  f32x4 oacc[3];
  #pragma unroll
  for (int nf=0;nf<3;nf++) oacc[nf] = (f32x4){0.f,0.f,0.f,0.f};
  #pragma unroll
  for (int ks=0;ks<4;ks++){
    int ko = ks*32 + g*8;
    bf16x8 asc[3];
    #pragma unroll
    for (int l=0;l<3;l++){
      #pragma unroll
      for (int i=0;i<8;i++) asc[l][i] = (short)f2bf(bfs(a[l][ks][i]) * lamA[l]);
    }
    #pragma unroll
    for (int nf=0;nf<3;nf++){
      bf16x8 bh = *reinterpret_cast<const bf16x8*>(WoutT + (size_t)(nf*16+rA)*128 + ko);
      bf16x8 bl = *reinterpret_cast<const bf16x8*>(WoutT + 6144 + (size_t)(nf*16+rA)*128 + ko);
      #pragma unroll
      for (int l=0;l<3;l++){
        oacc[nf] = __builtin_amdgcn_mfma_f32_16x16x32_bf16(asc[l], bh, oacc[nf], 0, 0, 0);
        oacc[nf] = __builtin_amdgcn_mfma_f32_16x16x32_bf16(asc[l], bl, oacc[nf], 0, 0, 0);
      }
    }
  }

  #pragma unroll
  for (int nf=0;nf<3;nf++){
    int col = nf*16 + rA;
    float bv = (col < 40) ? bout[col] : 0.f;
    #pragma unroll
    for (int r=0;r<4;r++){
      int row = r0 + g*4 + r;
      if (row < M && col < 40) out[(size_t)row*40 + col] = oacc[nf][r] + bv;
    }
  }
}

extern "C" void kernel_launch(void* const* d_in, const int* in_sizes, int n_in,
                              void* d_out, int out_size, void* d_ws, size_t ws_size,
                              hipStream_t stream)
{
  const float* x    = (const float*)d_in[0];
  const int*   ei   = (const int*)d_in[1];
  const float* W0   = (const float*)d_in[2];
  const float* as0  = (const float*)d_in[3];
  const float* ad0  = (const float*)d_in[4];
  const float* b0   = (const float*)d_in[5];
  const float* W12  = (const float*)d_in[6];
  const float* as12 = (const float*)d_in[7];
  const float* ad12 = (const float*)d_in[8];
  const float* b12  = (const float*)d_in[9];
  const float* Watt = (const float*)d_in[10];
  const float* aatt = (const float*)d_in[11];
  const float* Wout = (const float*)d_in[12];
  const float* bout = (const float*)d_in[13];
  const int N_ = in_sizes[0] / 128;
  const int E_ = in_sizes[1] / 2;
  const int Et = E_ + N_;
  const int nb = (N_ + 1023) >> 10;

  char* p = (char*)d_ws;
  auto carve = [&](size_t bytes)->char*{ char* r = p; p += (bytes + 255) & ~(size_t)255; return r; };
  unsigned short* htmp = (unsigned short*)carve((size_t)N_*128*2);
  unsigned short* h0   = (unsigned short*)carve((size_t)N_*128*2);
  unsigned short* h1   = (unsigned short*)carve((size_t)N_*128*2);
  unsigned short* h2   = (unsigned short*)carve((size_t)N_*128*2);
  unsigned short* wsT  = (unsigned short*)carve((size_t)(5*18432 + 48*128)*2);
  float* ssrc_s  = (float*)carve((size_t)N_*8*4);
  float* sdst_s  = (float*)carve((size_t)N_*8*4);
  int* offv      = (int*)carve((size_t)(N_+1)*4);
  int* bcnt      = (int*)carve((size_t)64*4);
  unsigned* bdata= (unsigned*)carve((size_t)64*BCAP*4);
  int* csr       = (int*)carve((size_t)(Et+8)*4);

  hipMemsetAsync(bcnt, 0, 64*4, stream);
  int gB = (Et + 2047)/2048;
  int gM = (N_+127)/128;
  k_prep_bucket<<<5+gB,256,0,stream>>>(W0, W12, Watt, as0, ad0, as12, ad12, Wout, wsT,
                                       ei, bcnt, bdata, E_, Et);
  k_bfinish_gemm0<<<nb+gM,512,0,stream>>>(bdata, bcnt, offv, csr, N_, nb,
                                          x, wsT, htmp, ssrc_s, sdst_s);

  int gA  = ((N_+7)/8)*2;
  int gF  = (N_+63)/64;
  unsigned short* hl[3] = {h0,h1,h2};
  for (int l=0;l<3;l++){
    const float* bb = (l==0)? b0 : b12 + (size_t)(l-1)*128;
    if (l > 0)
      k_gemm<<<gM,256,0,stream>>>(hl[l-1], wsT + (size_t)l*18432, htmp, ssrc_s, sdst_s, N_);
    k_aggregate<<<gA,256,0,stream>>>(offv, csr, htmp, ssrc_s, sdst_s, bb, hl[l], N_);
  }
  k_final4<<<gF,256,0,stream>>>(h0, h1, h2, wsT + (size_t)3*18432, aatt,
                                wsT + (size_t)4*18432, bout, (float*)d_out, N_);
}

// Round 16
// 234.199 us; speedup vs baseline: 1.0165x; 1.0165x over previous
//
#include <hip/hip_runtime.h>
#include <hip/hip_bf16.h>

typedef float f32x4 __attribute__((ext_vector_type(4)));
typedef short bf16x8 __attribute__((ext_vector_type(8)));

#define BCAP 20480   // per-bucket capacity (mean 17408, +24 sigma)

__device__ __forceinline__ float4 ld4(const float* p){ return *reinterpret_cast<const float4*>(p); }
__device__ __forceinline__ unsigned short f2bf(float f){
  unsigned int u = __float_as_uint(f);
  u = (u + 0x7fffu + ((u>>16)&1u)) >> 16;
  return (unsigned short)u;
}
__device__ __forceinline__ float bflo(unsigned int u){ return __uint_as_float(u<<16); }
__device__ __forceinline__ float bfhi(unsigned int u){ return __uint_as_float(u & 0xffff0000u); }
__device__ __forceinline__ float bfs(short s){ return __uint_as_float(((unsigned)(unsigned short)s)<<16); }
__device__ __forceinline__ float ftanh(float x){
  float e = __expf(2.f*x);
  return fmaf(-2.f, __builtin_amdgcn_rcpf(e+1.f), 1.f);
}

// =============== fused: weight prep (blocks 0..4) | edge bucketing (blocks 5+) ===============
__global__ __launch_bounds__(256) void k_prep_bucket(
    const float* __restrict__ W0, const float* __restrict__ W12, const float* __restrict__ Watt,
    const float* __restrict__ as0, const float* __restrict__ ad0,
    const float* __restrict__ as12, const float* __restrict__ ad12,
    const float* __restrict__ Wout, unsigned short* __restrict__ dst,
    const int* __restrict__ ei, int* __restrict__ bcnt, unsigned* __restrict__ bdata,
    int E_, int Et)
{
  __shared__ char smraw[32768];
  int b = blockIdx.x, t = threadIdx.x;
  if (b < 5){
    // ---------------- prep ----------------
    if (b == 4){
      unsigned short* wo = dst + (size_t)4*18432;
      for (int i=t; i<48*128; i+=256){
        int col = i>>7, k = i&127;
        float v = (col < 40) ? Wout[(size_t)k*40 + col] : 0.f;
        unsigned short hi = f2bf(v);
        float r = v - __uint_as_float(((unsigned)hi)<<16);
        wo[i] = hi;
        wo[48*128 + i] = f2bf(r);
      }
      return;
    }
    float* Wf = (float*)smraw;
    const float* W = (b==0) ? W0 : (b==3 ? Watt : W12 + (size_t)(b-1)*16384);
    unsigned short* out = dst + (size_t)b*18432;
    const float* as_ = (b==0) ? as0 : as12 + (size_t)(b-1)*128;
    const float* ad_ = (b==0) ? ad0 : ad12 + (size_t)(b-1)*128;

    for (int half=0; half<2; half++){
      #pragma unroll
      for (int p=0;p<8;p++){
        int i = p*256 + t;
        *reinterpret_cast<float4*>(&Wf[i*4]) = ld4(&W[(size_t)half*8192 + i*4]);
      }
      __syncthreads();
      {
        int col = t>>1, koff = (t&1)*32;
        #pragma unroll
        for (int j=0;j<4;j++){
          unsigned short tmp[8];
          #pragma unroll
          for (int q=0;q<8;q++) tmp[q] = f2bf(Wf[(koff + j*8 + q)*128 + col]);
          *reinterpret_cast<uint4*>(&out[col*128 + half*64 + koff + j*8]) = *reinterpret_cast<const uint4*>(tmp);
        }
      }
      {
        int ce = t>>4;
        int h  = ce & 7;
        if (b < 3){
          const float* av = (ce < 8) ? (as_ + h*16) : (ad_ + h*16);
          float avr[16];
          #pragma unroll
          for (int c2=0;c2<16;c2++) avr[c2] = av[c2];
          #pragma unroll
          for (int i=0;i<4;i++){
            int kl = (t&15) + i*16;
            float s = 0.f;
            #pragma unroll
            for (int c2=0;c2<16;c2++) s += Wf[kl*128 + h*16 + c2]*avr[c2];
            out[(128+ce)*128 + half*64 + kl] = f2bf(s);
          }
        } else {
          #pragma unroll
          for (int i=0;i<4;i++){
            int kl = (t&15) + i*16;
            out[(128+ce)*128 + half*64 + kl] = 0;
          }
        }
      }
      __syncthreads();
    }
    return;
  }
  // ---------------- bucket ----------------
  int* h    = (int*)smraw;
  int* base = (int*)(smraw + 256);
  if (t < 64) h[t] = 0;
  __syncthreads();
  int e0 = (b-5)*2048 + t;
  int dv[8], sv[8], rv[8];
  #pragma unroll
  for (int k=0;k<8;k++){
    int e = e0 + k*256;
    if (e < Et){
      int s, d;
      if (e < E_){ s = ei[e]; d = ei[E_+e]; } else { s = e-E_; d = s; }
      dv[k] = d; sv[k] = s;
      rv[k] = atomicAdd(&h[d>>10], 1);
    } else dv[k] = -1;
  }
  __syncthreads();
  if (t < 64 && h[t]) base[t] = atomicAdd(&bcnt[t], h[t]);
  __syncthreads();
  #pragma unroll
  for (int k=0;k<8;k++){
    if (dv[k] >= 0){
      int bk = dv[k]>>10;
      bdata[(size_t)bk*BCAP + base[bk] + rv[k]] = ((unsigned)(dv[k]&1023)<<17) | (unsigned)sv[k];
    }
  }
}

// =============== fused: CSR finish (blocks 0..nb-1) | layer-0 GEMM fp32-A (blocks nb+) ===============
__global__ __launch_bounds__(512) void k_bfinish_gemm0(
    const unsigned* __restrict__ bdata, const int* __restrict__ bcnt,
    int* __restrict__ off, int* __restrict__ csr, int N_, int nb,
    const float* __restrict__ x, const unsigned short* __restrict__ Bt,
    unsigned short* __restrict__ C, float* __restrict__ s_src, float* __restrict__ s_dst)
{
  __shared__ int c[1024];
  __shared__ int wsum[8];
  __shared__ int bbase_s;
  int t = threadIdx.x;
  if ((int)blockIdx.x < nb){
    int b = blockIdx.x;
    if (t < 64){
      int v = (t < nb) ? bcnt[t] : 0;
      int incl = v;
      #pragma unroll
      for (int d=1; d<64; d<<=1){ int u = __shfl_up(incl, d); if (t>=d) incl += u; }
      if (t == b) bbase_s = incl - v;
      if (b == 0 && t == 63) off[N_] = incl;
    }
    int cnt = bcnt[b];
    size_t lo = (size_t)b*BCAP;
    for (int i=t;i<1024;i+=512) c[i]=0;
    __syncthreads();
    for (int i=t; i<cnt; i+=512) atomicAdd(&c[bdata[lo+i]>>17], 1);
    __syncthreads();
    int c0 = c[2*t], c1 = c[2*t+1];
    int s = c0 + c1;
    int lane = t&63, w = t>>6;
    int incl = s;
    #pragma unroll
    for (int d=1; d<64; d<<=1){ int u = __shfl_up(incl, d); if (lane>=d) incl += u; }
    if (lane==63) wsum[w] = incl;
    __syncthreads();
    int wpre = 0;
    #pragma unroll
    for (int k=0;k<8;k++) if (k<w) wpre += wsum[k];
    int run = bbase_s + wpre + incl - s;
    int n = (b<<10) + 2*t;
    if (n   < N_) off[n]   = run;
    if (n+1 < N_) off[n+1] = run + c0;
    c[2*t]   = run;
    c[2*t+1] = run + c0;
    __syncthreads();
    for (int i=t; i<cnt; i+=512){
      unsigned p = bdata[lo+i];
      int pos = atomicAdd(&c[p>>17], 1);
      csr[pos] = (int)(p & 0x1FFFFu);
    }
    return;
  }
  // ---------------- gemm layer 0 (A = x, fp32) ----------------
  if (t >= 256) return;
  int lane = t & 63, w = t >> 6;
  int rA = lane & 15, g = lane >> 4;
  int r0 = (blockIdx.x - nb)*128 + w*32;
  f32x4 z = {0.f,0.f,0.f,0.f};
  f32x4 acc[2][9];
  #pragma unroll
  for (int mf=0;mf<2;mf++)
    #pragma unroll
    for (int nf=0;nf<9;nf++) acc[mf][nf] = z;

  int M = N_;
  int rowc0 = min(r0 + rA,      M-1);
  int rowc1 = min(r0 + 16 + rA, M-1);
  #pragma unroll
  for (int ks=0; ks<4; ks++){
    int ko = ks*32 + g*8;
    bf16x8 a0, a1;
    float4 v0 = ld4(&x[(size_t)rowc0*128 + ko]);
    float4 v1 = ld4(&x[(size_t)rowc0*128 + ko + 4]);
    float4 v2 = ld4(&x[(size_t)rowc1*128 + ko]);
    float4 v3 = ld4(&x[(size_t)rowc1*128 + ko + 4]);
    a0[0]=(short)f2bf(v0.x); a0[1]=(short)f2bf(v0.y); a0[2]=(short)f2bf(v0.z); a0[3]=(short)f2bf(v0.w);
    a0[4]=(short)f2bf(v1.x); a0[5]=(short)f2bf(v1.y); a0[6]=(short)f2bf(v1.z); a0[7]=(short)f2bf(v1.w);
    a1[0]=(short)f2bf(v2.x); a1[1]=(short)f2bf(v2.y); a1[2]=(short)f2bf(v2.z); a1[3]=(short)f2bf(v2.w);
    a1[4]=(short)f2bf(v3.x); a1[5]=(short)f2bf(v3.y); a1[6]=(short)f2bf(v3.z); a1[7]=(short)f2bf(v3.w);
    #pragma unroll
    for (int nf=0;nf<9;nf++){
      bf16x8 bf_ = *reinterpret_cast<const bf16x8*>(Bt + (size_t)(nf*16+rA)*128 + ko);
      acc[0][nf] = __builtin_amdgcn_mfma_f32_16x16x32_bf16(a0, bf_, acc[0][nf], 0, 0, 0);
      acc[1][nf] = __builtin_amdgcn_mfma_f32_16x16x32_bf16(a1, bf_, acc[1][nf], 0, 0, 0);
    }
  }

  #pragma unroll
  for (int mf=0;mf<2;mf++){
    #pragma unroll
    for (int r=0;r<4;r++){
      int row = r0 + mf*16 + g*4 + r;
      if (row < M){
        #pragma unroll
        for (int nf=0;nf<8;nf++) C[(size_t)row*128 + nf*16 + rA] = f2bf(acc[mf][nf][r]);
        float sv_ = acc[mf][8][r];
        if (rA < 8) s_src[(size_t)row*8 + rA]     = sv_;
        else        s_dst[(size_t)row*8 + rA - 8] = sv_;
      }
    }
  }
}

// =============== MFMA GEMM (no LDS): A[M,128]bf16 @ Bt[144,128]bf16 (layers 1,2) ===============
__global__ __launch_bounds__(256) void k_gemm(
    const unsigned short* __restrict__ A, const unsigned short* __restrict__ Bt,
    unsigned short* __restrict__ C, float* __restrict__ s_src, float* __restrict__ s_dst, int M)
{
  int t = threadIdx.x, lane = t & 63, w = t >> 6;
  int rA = lane & 15, g = lane >> 4;
  int r0 = blockIdx.x*128 + w*32;
  f32x4 z = {0.f,0.f,0.f,0.f};
  f32x4 acc[2][9];
  #pragma unroll
  for (int mf=0;mf<2;mf++)
    #pragma unroll
    for (int nf=0;nf<9;nf++) acc[mf][nf] = z;

  int rowc0 = min(r0 + rA,      M-1);
  int rowc1 = min(r0 + 16 + rA, M-1);
  #pragma unroll
  for (int ks=0; ks<4; ks++){
    int ko = ks*32 + g*8;
    bf16x8 a0 = *reinterpret_cast<const bf16x8*>(A + (size_t)rowc0*128 + ko);
    bf16x8 a1 = *reinterpret_cast<const bf16x8*>(A + (size_t)rowc1*128 + ko);
    #pragma unroll
    for (int nf=0;nf<9;nf++){
      bf16x8 bf_ = *reinterpret_cast<const bf16x8*>(Bt + (size_t)(nf*16+rA)*128 + ko);
      acc[0][nf] = __builtin_amdgcn_mfma_f32_16x16x32_bf16(a0, bf_, acc[0][nf], 0, 0, 0);
      acc[1][nf] = __builtin_amdgcn_mfma_f32_16x16x32_bf16(a1, bf_, acc[1][nf], 0, 0, 0);
    }
  }

  #pragma unroll
  for (int mf=0;mf<2;mf++){
    #pragma unroll
    for (int r=0;r<4;r++){
      int row = r0 + mf*16 + g*4 + r;
      if (row < M){
        #pragma unroll
        for (int nf=0;nf<8;nf++) C[(size_t)row*128 + nf*16 + rA] = f2bf(acc[mf][nf][r]);
        float sv_ = acc[mf][8][r];
        if (rA < 8) s_src[(size_t)row*8 + rA]     = sv_;
        else        s_dst[(size_t)row*8 + rA - 8] = sv_;
      }
    }
  }
}

// =============== softmax-aggregate: 2 nodes/wave, 16 lanes/row, 2 loads in flight ===============
// (round-14 proven version)
__global__ __launch_bounds__(256) void k_aggregate(
    const int* __restrict__ off, const int* __restrict__ csr,
    const unsigned short* __restrict__ htmp, const float* __restrict__ s_src,
    const float* __restrict__ s_dst, const float* __restrict__ bias,
    unsigned short* __restrict__ hout, int N_)
{
  __shared__ float esc[4][2][288];   // [wave][half][h*36 + e], e<32
  __shared__ int   ssrc[4][2][32];
  int w = threadIdx.x >> 6;
  int lane = threadIdx.x & 63;
  int half = lane >> 5;
  int l32  = lane & 31;
  int c2   = l32 & 15;
  int eo   = l32 >> 4;
  int myh  = c2 >> 1;
  int n = blockIdx.x*8 + w*2 + half;
  int base = 0, deg = 0;
  if (n < N_){ base = off[n]; deg = off[n+1] - base; }
  float sdv[8] = {0.f,0.f,0.f,0.f,0.f,0.f,0.f,0.f};
  if (n < N_){
    float4 sd0 = ld4(&s_dst[(size_t)n*8]);
    float4 sd1 = ld4(&s_dst[(size_t)n*8+4]);
    sdv[0]=sd0.x; sdv[1]=sd0.y; sdv[2]=sd0.z; sdv[3]=sd0.w;
    sdv[4]=sd1.x; sdv[5]=sd1.y; sdv[6]=sd1.z; sdv[7]=sd1.w;
  }
  float acc0=0.f,acc1=0.f,acc2=0.f,acc3=0.f,acc4=0.f,acc5=0.f,acc6=0.f,acc7=0.f;
  float dsum = 0.f;
  const char* hb = (const char*)htmp + (c2<<4);

  for (int cb=0; cb<deg; cb+=32){
    int cdeg = min(32, deg-cb);
    int srcj = 0;
    float ee[8];
    if (l32 < cdeg){
      srcj = csr[base+cb+l32];
      float4 a0 = ld4(&s_src[(size_t)srcj*8]);
      float4 a1 = ld4(&s_src[(size_t)srcj*8+4]);
      float sv[8] = {a0.x,a0.y,a0.z,a0.w,a1.x,a1.y,a1.z,a1.w};
      #pragma unroll
      for (int h=0;h<8;h++){
        float v = sv[h] + sdv[h];
        v = v > 0.f ? v : 0.2f*v;
        ee[h] = __expf(v);
      }
    } else {
      #pragma unroll
      for (int h=0;h<8;h++) ee[h] = 0.f;
    }
    ssrc[w][half][l32] = srcj;
    #pragma unroll
    for (int h=0;h<8;h++) esc[w][half][h*36 + l32] = ee[h];
    asm volatile("s_waitcnt lgkmcnt(0)" ::: "memory");
    __builtin_amdgcn_sched_barrier(0);

    for (int j=0; j<cdeg; j+=4){
      int e0 = j + eo;
      int e1 = j + 2 + eo;
      int s0 = ssrc[w][half][e0];
      int s1 = ssrc[w][half][e1];
      float ev0 = esc[w][half][myh*36 + e0];
      float ev1 = esc[w][half][myh*36 + e1];
      uint4 u0 = *reinterpret_cast<const uint4*>(hb + ((size_t)(unsigned)s0<<8));
      uint4 u1 = *reinterpret_cast<const uint4*>(hb + ((size_t)(unsigned)s1<<8));
      acc0 = fmaf(ev0, bflo(u0.x), acc0);
      acc1 = fmaf(ev0, bfhi(u0.x), acc1);
      acc2 = fmaf(ev0, bflo(u0.y), acc2);
      acc3 = fmaf(ev0, bfhi(u0.y), acc3);
      acc4 = fmaf(ev0, bflo(u0.z), acc4);
      acc5 = fmaf(ev0, bfhi(u0.z), acc5);
      acc6 = fmaf(ev0, bflo(u0.w), acc6);
      acc7 = fmaf(ev0, bfhi(u0.w), acc7);
      acc0 = fmaf(ev1, bflo(u1.x), acc0);
      acc1 = fmaf(ev1, bfhi(u1.x), acc1);
      acc2 = fmaf(ev1, bflo(u1.y), acc2);
      acc3 = fmaf(ev1, bfhi(u1.y), acc3);
      acc4 = fmaf(ev1, bflo(u1.z), acc4);
      acc5 = fmaf(ev1, bfhi(u1.z), acc5);
      acc6 = fmaf(ev1, bflo(u1.w), acc6);
      acc7 = fmaf(ev1, bfhi(u1.w), acc7);
      dsum += ev0 + ev1;
    }
  }
  acc0 += __shfl_xor(acc0, 16);
  acc1 += __shfl_xor(acc1, 16);
  acc2 += __shfl_xor(acc2, 16);
  acc3 += __shfl_xor(acc3, 16);
  acc4 += __shfl_xor(acc4, 16);
  acc5 += __shfl_xor(acc5, 16);
  acc6 += __shfl_xor(acc6, 16);
  acc7 += __shfl_xor(acc7, 16);
  dsum += __shfl_xor(dsum, 16);

  if (n < N_ && eo == 0){
    float inv = 1.f/(dsum + 1e-16f);
    float4 b0 = ld4(&bias[c2*8]);
    float4 b1 = ld4(&bias[c2*8+4]);
    float o0 = fmaf(acc0, inv, b0.x);
    float o1 = fmaf(acc1, inv, b0.y);
    float o2 = fmaf(acc2, inv, b0.z);
    float o3 = fmaf(acc3, inv, b0.w);
    float o4 = fmaf(acc4, inv, b1.x);
    float o5 = fmaf(acc5, inv, b1.y);
    float o6 = fmaf(acc6, inv, b1.z);
    float o7 = fmaf(acc7, inv, b1.w);
    o0 = o0>0.f ? o0 : (__expf(o0)-1.f);
    o1 = o1>0.f ? o1 : (__expf(o1)-1.f);
    o2 = o2>0.f ? o2 : (__expf(o2)-1.f);
    o3 = o3>0.f ? o3 : (__expf(o3)-1.f);
    o4 = o4>0.f ? o4 : (__expf(o4)-1.f);
    o5 = o5>0.f ? o5 : (__expf(o5)-1.f);
    o6 = o6>0.f ? o6 : (__expf(o6)-1.f);
    o7 = o7>0.f ? o7 : (__expf(o7)-1.f);
    uint4 pk;
    pk.x = (unsigned)f2bf(o0) | ((unsigned)f2bf(o1)<<16);
    pk.y = (unsigned)f2bf(o2) | ((unsigned)f2bf(o3)<<16);
    pk.z = (unsigned)f2bf(o4) | ((unsigned)f2bf(o5)<<16);
    pk.w = (unsigned)f2bf(o6) | ((unsigned)f2bf(o7)<<16);
    *reinterpret_cast<uint4*>(&hout[(size_t)n*128 + c2*8]) = pk;
  }
}

// =============== fused final v4: A-frag preload + B-share across layers ===============
// NOTE: no min-waves clamp ((256,4) caused 64-VGPR cap -> 134 MB spill, rounds 5/6).
__global__ __launch_bounds__(256) void k_final4(
    const unsigned short* __restrict__ h0, const unsigned short* __restrict__ h1,
    const unsigned short* __restrict__ h2,
    const unsigned short* __restrict__ WattT, const float* __restrict__ aatt,
    const unsigned short* __restrict__ WoutT,  // [48][128] hi, then [48][128] lo
    const float* __restrict__ bout, float* __restrict__ out, int M)
{
  int t = threadIdx.x, lane = t & 63, w = t >> 6;
  int rA = lane & 15, g = lane >> 4;
  int r0 = blockIdx.x*64 + w*16;
  int rowc = min(r0 + rA, M-1);

  float av[8];
  #pragma unroll
  for (int nf=0;nf<8;nf++) av[nf] = aatt[nf*16 + rA];

  bf16x8 a[3][4];
  #pragma unroll
  for (int ks=0;ks<4;ks++){
    int ko = ks*32 + g*8;
    a[0][ks] = *reinterpret_cast<const bf16x8*>(h0 + (size_t)rowc*128 + ko);
    a[1][ks] = *reinterpret_cast<const bf16x8*>(h1 + (size_t)rowc*128 + ko);
    a[2][ks] = *reinterpret_cast<const bf16x8*>(h2 + (size_t)rowc*128 + ko);
  }

  float sc[3][4];
  #pragma unroll
  for (int l=0;l<3;l++)
    #pragma unroll
    for (int r=0;r<4;r++) sc[l][r] = 0.f;

  #pragma unroll
  for (int ch=0; ch<4; ch++){
    f32x4 acc[3][2];
    #pragma unroll
    for (int l=0;l<3;l++){ acc[l][0] = (f32x4){0.f,0.f,0.f,0.f}; acc[l][1] = (f32x4){0.f,0.f,0.f,0.f}; }
    #pragma unroll
    for (int ks=0; ks<4; ks++){
      int ko = ks*32 + g*8;
      bf16x8 b0 = *reinterpret_cast<const bf16x8*>(WattT + (size_t)((ch*2+0)*16+rA)*128 + ko);
      bf16x8 b1 = *reinterpret_cast<const bf16x8*>(WattT + (size_t)((ch*2+1)*16+rA)*128 + ko);
      #pragma unroll
      for (int l=0;l<3;l++){
        acc[l][0] = __builtin_amdgcn_mfma_f32_16x16x32_bf16(a[l][ks], b0, acc[l][0], 0, 0, 0);
        acc[l][1] = __builtin_amdgcn_mfma_f32_16x16x32_bf16(a[l][ks], b1, acc[l][1], 0, 0, 0);
      }
    }
    float w0 = av[ch*2], w1 = av[ch*2+1];
    #pragma unroll
    for (int l=0;l<3;l++)
      #pragma unroll
      for (int r=0;r<4;r++)
        sc[l][r] += ftanh(acc[l][0][r])*w0 + ftanh(acc[l][1][r])*w1;
  }
  #pragma unroll
  for (int l=0;l<3;l++)
    #pragma unroll
    for (int r=0;r<4;r++){
      float s = sc[l][r];
      s += __shfl_xor(s, 1);
      s += __shfl_xor(s, 2);
      s += __shfl_xor(s, 4);
      s += __shfl_xor(s, 8);
      sc[l][r] = s;
    }

  float lam[3][4];
  #pragma unroll
  for (int r=0;r<4;r++){
    float m = fmaxf(sc[0][r], fmaxf(sc[1][r], sc[2][r]));
    float e0 = __expf(sc[0][r]-m), e1 = __expf(sc[1][r]-m), e2 = __expf(sc[2][r]-m);
    float inv = 1.f/(e0+e1+e2);
    lam[0][r]=e0*inv; lam[1][r]=e1*inv; lam[2][r]=e2*inv;
  }
  int rsel = rA & 3;
  int srcLane = ((rA>>2)<<4) | rA;
  float p0 = rsel==0 ? lam[0][0] : rsel==1 ? lam[0][1] : rsel==2 ? lam[0][2] : lam[0][3];
  float p1 = rsel==0 ? lam[1][0] : rsel==1 ? lam[1][1] : rsel==2 ? lam[1][2] : lam[1][3];
  float p2 = rsel==0 ? lam[2][0] : rsel==1 ? lam[2][1] : rsel==2 ? lam[2][2] : lam[2][3];
  float lamA[3];
  lamA[0] = __shfl(p0, srcLane);
  lamA[1] = __shfl(p1, srcLane);
  lamA[2] = __shfl(p2, srcLane);

  f32x4 oacc[3];
  #pragma unroll
  for (int nf=0;nf<3;nf++) oacc[nf] = (f32x4){0.f,0.f,0.f,0.f};
  #pragma unroll
  for (int ks=0;ks<4;ks++){
    int ko = ks*32 + g*8;
    bf16x8 asc[3];
    #pragma unroll
    for (int l=0;l<3;l++){
      #pragma unroll
      for (int i=0;i<8;i++) asc[l][i] = (short)f2bf(bfs(a[l][ks][i]) * lamA[l]);
    }
    #pragma unroll
    for (int nf=0;nf<3;nf++){
      bf16x8 bh = *reinterpret_cast<const bf16x8*>(WoutT + (size_t)(nf*16+rA)*128 + ko);
      bf16x8 bl = *reinterpret_cast<const bf16x8*>(WoutT + 6144 + (size_t)(nf*16+rA)*128 + ko);
      #pragma unroll
      for (int l=0;l<3;l++){
        oacc[nf] = __builtin_amdgcn_mfma_f32_16x16x32_bf16(asc[l], bh, oacc[nf], 0, 0, 0);
        oacc[nf] = __builtin_amdgcn_mfma_f32_16x16x32_bf16(asc[l], bl, oacc[nf], 0, 0, 0);
      }
    }
  }

  #pragma unroll
  for (int nf=0;nf<3;nf++){
    int col = nf*16 + rA;
    float bv = (col < 40) ? bout[col] : 0.f;
    #pragma unroll
    for (int r=0;r<4;r++){
      int row = r0 + g*4 + r;
      if (row < M && col < 40) out[(size_t)row*40 + col] = oacc[nf][r] + bv;
    }
  }
}

extern "C" void kernel_launch(void* const* d_in, const int* in_sizes, int n_in,
                              void* d_out, int out_size, void* d_ws, size_t ws_size,
                              hipStream_t stream)
{
  const float* x    = (const float*)d_in[0];
  const int*   ei   = (const int*)d_in[1];
  const float* W0   = (const float*)d_in[2];
  const float* as0  = (const float*)d_in[3];
  const float* ad0  = (const float*)d_in[4];
  const float* b0   = (const float*)d_in[5];
  const float* W12  = (const float*)d_in[6];
  const float* as12 = (const float*)d_in[7];
  const float* ad12 = (const float*)d_in[8];
  const float* b12  = (const float*)d_in[9];
  const float* Watt = (const float*)d_in[10];
  const float* aatt = (const float*)d_in[11];
  const float* Wout = (const float*)d_in[12];
  const float* bout = (const float*)d_in[13];
  const int N_ = in_sizes[0] / 128;
  const int E_ = in_sizes[1] / 2;
  const int Et = E_ + N_;
  const int nb = (N_ + 1023) >> 10;

  char* p = (char*)d_ws;
  auto carve = [&](size_t bytes)->char*{ char* r = p; p += (bytes + 255) & ~(size_t)255; return r; };
  unsigned short* htmp = (unsigned short*)carve((size_t)N_*128*2);
  unsigned short* h0   = (unsigned short*)carve((size_t)N_*128*2);
  unsigned short* h1   = (unsigned short*)carve((size_t)N_*128*2);
  unsigned short* h2   = (unsigned short*)carve((size_t)N_*128*2);
  unsigned short* wsT  = (unsigned short*)carve((size_t)(5*18432 + 48*128)*2);
  float* ssrc_s  = (float*)carve((size_t)N_*8*4);
  float* sdst_s  = (float*)carve((size_t)N_*8*4);
  int* offv      = (int*)carve((size_t)(N_+1)*4);
  int* bcnt      = (int*)carve((size_t)64*4);
  unsigned* bdata= (unsigned*)carve((size_t)64*BCAP*4);
  int* csr       = (int*)carve((size_t)(Et+8)*4);

  hipMemsetAsync(bcnt, 0, 64*4, stream);
  int gB = (Et + 2047)/2048;
  int gM = (N_+127)/128;
  k_prep_bucket<<<5+gB,256,0,stream>>>(W0, W12, Watt, as0, ad0, as12, ad12, Wout, wsT,
                                       ei, bcnt, bdata, E_, Et);
  k_bfinish_gemm0<<<nb+gM,512,0,stream>>>(bdata, bcnt, offv, csr, N_, nb,
                                          x, wsT, htmp, ssrc_s, sdst_s);

  int gN8 = (N_+7)/8;
  int gF  = (N_+63)/64;
  unsigned short* hl[3] = {h0,h1,h2};
  for (int l=0;l<3;l++){
    const float* bb = (l==0)? b0 : b12 + (size_t)(l-1)*128;
    if (l > 0)
      k_gemm<<<gM,256,0,stream>>>(hl[l-1], wsT + (size_t)l*18432, htmp, ssrc_s, sdst_s, N_);
    k_aggregate<<<gN8,256,0,stream>>>(offv, csr, htmp, ssrc_s, sdst_s, bb, hl[l], N_);
  }
  k_final4<<<gF,256,0,stream>>>(h0, h1, h2, wsT + (size_t)3*18432, aatt,
                                wsT + (size_t)4*18432, bout, (float*)d_out, N_);
}

// Round 17
// 226.616 us; speedup vs baseline: 1.0505x; 1.0335x over previous
//
#include <hip/hip_runtime.h>
#include <hip/hip_bf16.h>

typedef float f32x4 __attribute__((ext_vector_type(4)));
typedef short bf16x8 __attribute__((ext_vector_type(8)));

#define BCAP 20480   // per-bucket capacity (mean 17408, +24 sigma)

__device__ __forceinline__ float4 ld4(const float* p){ return *reinterpret_cast<const float4*>(p); }
__device__ __forceinline__ unsigned short f2bf(float f){
  unsigned int u = __float_as_uint(f);
  u = (u + 0x7fffu + ((u>>16)&1u)) >> 16;
  return (unsigned short)u;
}
__device__ __forceinline__ float bflo(unsigned int u){ return __uint_as_float(u<<16); }
__device__ __forceinline__ float bfhi(unsigned int u){ return __uint_as_float(u & 0xffff0000u); }
__device__ __forceinline__ float bfs(short s){ return __uint_as_float(((unsigned)(unsigned short)s)<<16); }
__device__ __forceinline__ float ftanh(float x){
  float e = __expf(2.f*x);
  return fmaf(-2.f, __builtin_amdgcn_rcpf(e+1.f), 1.f);
}

// =============== fused: weight prep (blocks 0..4) | edge bucketing (blocks 5+) ===============
__global__ __launch_bounds__(256) void k_prep_bucket(
    const float* __restrict__ W0, const float* __restrict__ W12, const float* __restrict__ Watt,
    const float* __restrict__ as0, const float* __restrict__ ad0,
    const float* __restrict__ as12, const float* __restrict__ ad12,
    const float* __restrict__ Wout, unsigned short* __restrict__ dst,
    const int* __restrict__ ei, int* __restrict__ bcnt, unsigned* __restrict__ bdata,
    int E_, int Et)
{
  __shared__ char smraw[32768];
  int b = blockIdx.x, t = threadIdx.x;
  if (b < 5){
    if (b == 4){
      unsigned short* wo = dst + (size_t)4*18432;
      for (int i=t; i<48*128; i+=256){
        int col = i>>7, k = i&127;
        float v = (col < 40) ? Wout[(size_t)k*40 + col] : 0.f;
        unsigned short hi = f2bf(v);
        float r = v - __uint_as_float(((unsigned)hi)<<16);
        wo[i] = hi;
        wo[48*128 + i] = f2bf(r);
      }
      return;
    }
    float* Wf = (float*)smraw;
    const float* W = (b==0) ? W0 : (b==3 ? Watt : W12 + (size_t)(b-1)*16384);
    unsigned short* out = dst + (size_t)b*18432;
    const float* as_ = (b==0) ? as0 : as12 + (size_t)(b-1)*128;
    const float* ad_ = (b==0) ? ad0 : ad12 + (size_t)(b-1)*128;

    for (int half=0; half<2; half++){
      #pragma unroll
      for (int p=0;p<8;p++){
        int i = p*256 + t;
        *reinterpret_cast<float4*>(&Wf[i*4]) = ld4(&W[(size_t)half*8192 + i*4]);
      }
      __syncthreads();
      {
        int col = t>>1, koff = (t&1)*32;
        #pragma unroll
        for (int j=0;j<4;j++){
          unsigned short tmp[8];
          #pragma unroll
          for (int q=0;q<8;q++) tmp[q] = f2bf(Wf[(koff + j*8 + q)*128 + col]);
          *reinterpret_cast<uint4*>(&out[col*128 + half*64 + koff + j*8]) = *reinterpret_cast<const uint4*>(tmp);
        }
      }
      {
        int ce = t>>4;
        int h  = ce & 7;
        if (b < 3){
          const float* av = (ce < 8) ? (as_ + h*16) : (ad_ + h*16);
          float avr[16];
          #pragma unroll
          for (int c2=0;c2<16;c2++) avr[c2] = av[c2];
          #pragma unroll
          for (int i=0;i<4;i++){
            int kl = (t&15) + i*16;
            float s = 0.f;
            #pragma unroll
            for (int c2=0;c2<16;c2++) s += Wf[kl*128 + h*16 + c2]*avr[c2];
            out[(128+ce)*128 + half*64 + kl] = f2bf(s);
          }
        } else {
          #pragma unroll
          for (int i=0;i<4;i++){
            int kl = (t&15) + i*16;
            out[(128+ce)*128 + half*64 + kl] = 0;
          }
        }
      }
      __syncthreads();
    }
    return;
  }
  // ---------------- bucket ----------------
  int* h    = (int*)smraw;
  int* base = (int*)(smraw + 256);
  if (t < 64) h[t] = 0;
  __syncthreads();
  int e0 = (b-5)*2048 + t;
  int dv[8], sv[8], rv[8];
  #pragma unroll
  for (int k=0;k<8;k++){
    int e = e0 + k*256;
    if (e < Et){
      int s, d;
      if (e < E_){ s = ei[e]; d = ei[E_+e]; } else { s = e-E_; d = s; }
      dv[k] = d; sv[k] = s;
      rv[k] = atomicAdd(&h[d>>10], 1);
    } else dv[k] = -1;
  }
  __syncthreads();
  if (t < 64 && h[t]) base[t] = atomicAdd(&bcnt[t], h[t]);
  __syncthreads();
  #pragma unroll
  for (int k=0;k<8;k++){
    if (dv[k] >= 0){
      int bk = dv[k]>>10;
      bdata[(size_t)bk*BCAP + base[bk] + rv[k]] = ((unsigned)(dv[k]&1023)<<17) | (unsigned)sv[k];
    }
  }
}

// =============== fused: CSR finish (blocks 0..nb-1) | layer-0 GEMM fp32-A (blocks nb+) ===============
__global__ __launch_bounds__(512) void k_bfinish_gemm0(
    const unsigned* __restrict__ bdata, const int* __restrict__ bcnt,
    int* __restrict__ off, int* __restrict__ csr, int N_, int nb,
    const float* __restrict__ x, const unsigned short* __restrict__ Bt,
    unsigned short* __restrict__ C, float* __restrict__ s_src, float* __restrict__ s_dst)
{
  __shared__ int c[1024];
  __shared__ int wsum[8];
  __shared__ int bbase_s;
  int t = threadIdx.x;
  if ((int)blockIdx.x < nb){
    int b = blockIdx.x;
    if (t < 64){
      int v = (t < nb) ? bcnt[t] : 0;
      int incl = v;
      #pragma unroll
      for (int d=1; d<64; d<<=1){ int u = __shfl_up(incl, d); if (t>=d) incl += u; }
      if (t == b) bbase_s = incl - v;
      if (b == 0 && t == 63) off[N_] = incl;
    }
    int cnt = bcnt[b];
    size_t lo = (size_t)b*BCAP;
    for (int i=t;i<1024;i+=512) c[i]=0;
    __syncthreads();
    for (int i=t; i<cnt; i+=512) atomicAdd(&c[bdata[lo+i]>>17], 1);
    __syncthreads();
    int c0 = c[2*t], c1 = c[2*t+1];
    int s = c0 + c1;
    int lane = t&63, w = t>>6;
    int incl = s;
    #pragma unroll
    for (int d=1; d<64; d<<=1){ int u = __shfl_up(incl, d); if (lane>=d) incl += u; }
    if (lane==63) wsum[w] = incl;
    __syncthreads();
    int wpre = 0;
    #pragma unroll
    for (int k=0;k<8;k++) if (k<w) wpre += wsum[k];
    int run = bbase_s + wpre + incl - s;
    int n = (b<<10) + 2*t;
    if (n   < N_) off[n]   = run;
    if (n+1 < N_) off[n+1] = run + c0;
    c[2*t]   = run;
    c[2*t+1] = run + c0;
    __syncthreads();
    for (int i=t; i<cnt; i+=512){
      unsigned p = bdata[lo+i];
      int pos = atomicAdd(&c[p>>17], 1);
      csr[pos] = (int)(p & 0x1FFFFu);
    }
    return;
  }
  // ---------------- gemm layer 0 (A = x, fp32) ----------------
  if (t >= 256) return;
  int lane = t & 63, w = t >> 6;
  int rA = lane & 15, g = lane >> 4;
  int r0 = (blockIdx.x - nb)*128 + w*32;
  f32x4 z = {0.f,0.f,0.f,0.f};
  f32x4 acc[2][9];
  #pragma unroll
  for (int mf=0;mf<2;mf++)
    #pragma unroll
    for (int nf=0;nf<9;nf++) acc[mf][nf] = z;

  int M = N_;
  int rowc0 = min(r0 + rA,      M-1);
  int rowc1 = min(r0 + 16 + rA, M-1);
  #pragma unroll
  for (int ks=0; ks<4; ks++){
    int ko = ks*32 + g*8;
    bf16x8 a0, a1;
    float4 v0 = ld4(&x[(size_t)rowc0*128 + ko]);
    float4 v1 = ld4(&x[(size_t)rowc0*128 + ko + 4]);
    float4 v2 = ld4(&x[(size_t)rowc1*128 + ko]);
    float4 v3 = ld4(&x[(size_t)rowc1*128 + ko + 4]);
    a0[0]=(short)f2bf(v0.x); a0[1]=(short)f2bf(v0.y); a0[2]=(short)f2bf(v0.z); a0[3]=(short)f2bf(v0.w);
    a0[4]=(short)f2bf(v1.x); a0[5]=(short)f2bf(v1.y); a0[6]=(short)f2bf(v1.z); a0[7]=(short)f2bf(v1.w);
    a1[0]=(short)f2bf(v2.x); a1[1]=(short)f2bf(v2.y); a1[2]=(short)f2bf(v2.z); a1[3]=(short)f2bf(v2.w);
    a1[4]=(short)f2bf(v3.x); a1[5]=(short)f2bf(v3.y); a1[6]=(short)f2bf(v3.z); a1[7]=(short)f2bf(v3.w);
    #pragma unroll
    for (int nf=0;nf<9;nf++){
      bf16x8 bf_ = *reinterpret_cast<const bf16x8*>(Bt + (size_t)(nf*16+rA)*128 + ko);
      acc[0][nf] = __builtin_amdgcn_mfma_f32_16x16x32_bf16(a0, bf_, acc[0][nf], 0, 0, 0);
      acc[1][nf] = __builtin_amdgcn_mfma_f32_16x16x32_bf16(a1, bf_, acc[1][nf], 0, 0, 0);
    }
  }

  #pragma unroll
  for (int mf=0;mf<2;mf++){
    #pragma unroll
    for (int r=0;r<4;r++){
      int row = r0 + mf*16 + g*4 + r;
      if (row < M){
        #pragma unroll
        for (int nf=0;nf<8;nf++) C[(size_t)row*128 + nf*16 + rA] = f2bf(acc[mf][nf][r]);
        float sv_ = acc[mf][8][r];
        if (rA < 8) s_src[(size_t)row*8 + rA]     = sv_;
        else        s_dst[(size_t)row*8 + rA - 8] = sv_;
      }
    }
  }
}

// =============== softmax-aggregate (+ optional fused next-layer GEMM for the block's rows) ===============
// Phase A: round-14 aggregate (2 nodes/wave). eo==0 lanes also deposit the output row in LDS.
// Phase B (FUSE): waves 0-1 compute htmp_next rows for this block's 8 nodes via MFMA from LDS.
// Double-buffered htmp/s_src/s_dst between layers avoids phase-A/phase-B races across blocks.
template<int FUSE>
__global__ __launch_bounds__(256) void k_agg_gemm(
    const int* __restrict__ off, const int* __restrict__ csr,
    const unsigned short* __restrict__ htmp, const float* __restrict__ s_src,
    const float* __restrict__ s_dst, const float* __restrict__ bias,
    unsigned short* __restrict__ hout, int N_,
    const unsigned short* __restrict__ Btn,  // next layer [144][128] bf16 (FUSE only)
    unsigned short* __restrict__ Cn, float* __restrict__ s_srcn, float* __restrict__ s_dstn)
{
  __shared__ float esc[4][2][288];
  __shared__ int   ssrc[4][2][32];
  __shared__ unsigned short hrows[8][128];
  int w = threadIdx.x >> 6;
  int lane = threadIdx.x & 63;
  int half = lane >> 5;
  int l32  = lane & 31;
  int c2   = l32 & 15;
  int eo   = l32 >> 4;
  int myh  = c2 >> 1;
  int n = blockIdx.x*8 + w*2 + half;
  int base = 0, deg = 0;
  if (n < N_){ base = off[n]; deg = off[n+1] - base; }
  float sdv[8] = {0.f,0.f,0.f,0.f,0.f,0.f,0.f,0.f};
  if (n < N_){
    float4 sd0 = ld4(&s_dst[(size_t)n*8]);
    float4 sd1 = ld4(&s_dst[(size_t)n*8+4]);
    sdv[0]=sd0.x; sdv[1]=sd0.y; sdv[2]=sd0.z; sdv[3]=sd0.w;
    sdv[4]=sd1.x; sdv[5]=sd1.y; sdv[6]=sd1.z; sdv[7]=sd1.w;
  }
  float acc0=0.f,acc1=0.f,acc2=0.f,acc3=0.f,acc4=0.f,acc5=0.f,acc6=0.f,acc7=0.f;
  float dsum = 0.f;
  const char* hb = (const char*)htmp + (c2<<4);

  for (int cb=0; cb<deg; cb+=32){
    int cdeg = min(32, deg-cb);
    int srcj = 0;
    float ee[8];
    if (l32 < cdeg){
      srcj = csr[base+cb+l32];
      float4 a0 = ld4(&s_src[(size_t)srcj*8]);
      float4 a1 = ld4(&s_src[(size_t)srcj*8+4]);
      float sv[8] = {a0.x,a0.y,a0.z,a0.w,a1.x,a1.y,a1.z,a1.w};
      #pragma unroll
      for (int h=0;h<8;h++){
        float v = sv[h] + sdv[h];
        v = v > 0.f ? v : 0.2f*v;
        ee[h] = __expf(v);
      }
    } else {
      #pragma unroll
      for (int h=0;h<8;h++) ee[h] = 0.f;
    }
    ssrc[w][half][l32] = srcj;
    #pragma unroll
    for (int h=0;h<8;h++) esc[w][half][h*36 + l32] = ee[h];
    asm volatile("s_waitcnt lgkmcnt(0)" ::: "memory");
    __builtin_amdgcn_sched_barrier(0);

    for (int j=0; j<cdeg; j+=4){
      int e0 = j + eo;
      int e1 = j + 2 + eo;
      int s0 = ssrc[w][half][e0];
      int s1 = ssrc[w][half][e1];
      float ev0 = esc[w][half][myh*36 + e0];
      float ev1 = esc[w][half][myh*36 + e1];
      uint4 u0 = *reinterpret_cast<const uint4*>(hb + ((size_t)(unsigned)s0<<8));
      uint4 u1 = *reinterpret_cast<const uint4*>(hb + ((size_t)(unsigned)s1<<8));
      acc0 = fmaf(ev0, bflo(u0.x), acc0);
      acc1 = fmaf(ev0, bfhi(u0.x), acc1);
      acc2 = fmaf(ev0, bflo(u0.y), acc2);
      acc3 = fmaf(ev0, bfhi(u0.y), acc3);
      acc4 = fmaf(ev0, bflo(u0.z), acc4);
      acc5 = fmaf(ev0, bfhi(u0.z), acc5);
      acc6 = fmaf(ev0, bflo(u0.w), acc6);
      acc7 = fmaf(ev0, bfhi(u0.w), acc7);
      acc0 = fmaf(ev1, bflo(u1.x), acc0);
      acc1 = fmaf(ev1, bfhi(u1.x), acc1);
      acc2 = fmaf(ev1, bflo(u1.y), acc2);
      acc3 = fmaf(ev1, bfhi(u1.y), acc3);
      acc4 = fmaf(ev1, bflo(u1.z), acc4);
      acc5 = fmaf(ev1, bfhi(u1.z), acc5);
      acc6 = fmaf(ev1, bflo(u1.w), acc6);
      acc7 = fmaf(ev1, bfhi(u1.w), acc7);
      dsum += ev0 + ev1;
    }
  }
  acc0 += __shfl_xor(acc0, 16);
  acc1 += __shfl_xor(acc1, 16);
  acc2 += __shfl_xor(acc2, 16);
  acc3 += __shfl_xor(acc3, 16);
  acc4 += __shfl_xor(acc4, 16);
  acc5 += __shfl_xor(acc5, 16);
  acc6 += __shfl_xor(acc6, 16);
  acc7 += __shfl_xor(acc7, 16);
  dsum += __shfl_xor(dsum, 16);

  if (n < N_ && eo == 0){
    float inv = 1.f/(dsum + 1e-16f);
    float4 b0 = ld4(&bias[c2*8]);
    float4 b1 = ld4(&bias[c2*8+4]);
    float o0 = fmaf(acc0, inv, b0.x);
    float o1 = fmaf(acc1, inv, b0.y);
    float o2 = fmaf(acc2, inv, b0.z);
    float o3 = fmaf(acc3, inv, b0.w);
    float o4 = fmaf(acc4, inv, b1.x);
    float o5 = fmaf(acc5, inv, b1.y);
    float o6 = fmaf(acc6, inv, b1.z);
    float o7 = fmaf(acc7, inv, b1.w);
    o0 = o0>0.f ? o0 : (__expf(o0)-1.f);
    o1 = o1>0.f ? o1 : (__expf(o1)-1.f);
    o2 = o2>0.f ? o2 : (__expf(o2)-1.f);
    o3 = o3>0.f ? o3 : (__expf(o3)-1.f);
    o4 = o4>0.f ? o4 : (__expf(o4)-1.f);
    o5 = o5>0.f ? o5 : (__expf(o5)-1.f);
    o6 = o6>0.f ? o6 : (__expf(o6)-1.f);
    o7 = o7>0.f ? o7 : (__expf(o7)-1.f);
    uint4 pk;
    pk.x = (unsigned)f2bf(o0) | ((unsigned)f2bf(o1)<<16);
    pk.y = (unsigned)f2bf(o2) | ((unsigned)f2bf(o3)<<16);
    pk.z = (unsigned)f2bf(o4) | ((unsigned)f2bf(o5)<<16);
    pk.w = (unsigned)f2bf(o6) | ((unsigned)f2bf(o7)<<16);
    *reinterpret_cast<uint4*>(&hout[(size_t)n*128 + c2*8]) = pk;
    if (FUSE)
      *reinterpret_cast<uint4*>(&hrows[w*2+half][c2*8]) = pk;
  }

  if (FUSE){
    __syncthreads();
    // ---- phase B: htmp_next rows for this block's 8 nodes (waves 0,1) ----
    if (w < 2){
      int rA2 = lane & 15, g2 = lane >> 4;
      int rr = rA2 & 7;   // A rows 8..15 duplicate 0..7 (outputs discarded)
      bf16x8 a2[4];
      #pragma unroll
      for (int ks=0;ks<4;ks++)
        a2[ks] = *reinterpret_cast<const bf16x8*>(&hrows[rr][ks*32 + g2*8]);
      int n0 = blockIdx.x*8;
      int nfLo = (w==0) ? 0 : 5;
      int nfHi = (w==0) ? 5 : 9;
      for (int nf=nfLo; nf<nfHi; nf++){
        f32x4 acc2 = {0.f,0.f,0.f,0.f};
        #pragma unroll
        for (int ks=0;ks<4;ks++){
          bf16x8 bf_ = *reinterpret_cast<const bf16x8*>(Btn + (size_t)(nf*16+rA2)*128 + ks*32 + g2*8);
          acc2 = __builtin_amdgcn_mfma_f32_16x16x32_bf16(a2[ks], bf_, acc2, 0, 0, 0);
        }
        if (g2 < 2){
          #pragma unroll
          for (int r=0;r<4;r++){
            int row = g2*4 + r;
            int n2 = n0 + row;
            if (n2 < N_){
              if (nf < 8) Cn[(size_t)n2*128 + nf*16 + rA2] = f2bf(acc2[r]);
              else {
                if (rA2 < 8) s_srcn[(size_t)n2*8 + rA2]     = acc2[r];
                else         s_dstn[(size_t)n2*8 + rA2 - 8] = acc2[r];
              }
            }
          }
        }
      }
    }
  }
}

// =============== fused final v4: A-frag preload + B-share across layers ===============
// NOTE: no min-waves clamp ((256,4) caused 64-VGPR cap -> 134 MB spill, rounds 5/6).
__global__ __launch_bounds__(256) void k_final4(
    const unsigned short* __restrict__ h0, const unsigned short* __restrict__ h1,
    const unsigned short* __restrict__ h2,
    const unsigned short* __restrict__ WattT, const float* __restrict__ aatt,
    const unsigned short* __restrict__ WoutT,  // [48][128] hi, then [48][128] lo
    const float* __restrict__ bout, float* __restrict__ out, int M)
{
  int t = threadIdx.x, lane = t & 63, w = t >> 6;
  int rA = lane & 15, g = lane >> 4;
  int r0 = blockIdx.x*64 + w*16;
  int rowc = min(r0 + rA, M-1);

  float av[8];
  #pragma unroll
  for (int nf=0;nf<8;nf++) av[nf] = aatt[nf*16 + rA];

  bf16x8 a[3][4];
  #pragma unroll
  for (int ks=0;ks<4;ks++){
    int ko = ks*32 + g*8;
    a[0][ks] = *reinterpret_cast<const bf16x8*>(h0 + (size_t)rowc*128 + ko);
    a[1][ks] = *reinterpret_cast<const bf16x8*>(h1 + (size_t)rowc*128 + ko);
    a[2][ks] = *reinterpret_cast<const bf16x8*>(h2 + (size_t)rowc*128 + ko);
  }

  float sc[3][4];
  #pragma unroll
  for (int l=0;l<3;l++)
    #pragma unroll
    for (int r=0;r<4;r++) sc[l][r] = 0.f;

  #pragma unroll
  for (int ch=0; ch<4; ch++){
    f32x4 acc[3][2];
    #pragma unroll
    for (int l=0;l<3;l++){ acc[l][0] = (f32x4){0.f,0.f,0.f,0.f}; acc[l][1] = (f32x4){0.f,0.f,0.f,0.f}; }
    #pragma unroll
    for (int ks=0; ks<4; ks++){
      int ko = ks*32 + g*8;
      bf16x8 b0 = *reinterpret_cast<const bf16x8*>(WattT + (size_t)((ch*2+0)*16+rA)*128 + ko);
      bf16x8 b1 = *reinterpret_cast<const bf16x8*>(WattT + (size_t)((ch*2+1)*16+rA)*128 + ko);
      #pragma unroll
      for (int l=0;l<3;l++){
        acc[l][0] = __builtin_amdgcn_mfma_f32_16x16x32_bf16(a[l][ks], b0, acc[l][0], 0, 0, 0);
        acc[l][1] = __builtin_amdgcn_mfma_f32_16x16x32_bf16(a[l][ks], b1, acc[l][1], 0, 0, 0);
      }
    }
    float w0 = av[ch*2], w1 = av[ch*2+1];
    #pragma unroll
    for (int l=0;l<3;l++)
      #pragma unroll
      for (int r=0;r<4;r++)
        sc[l][r] += ftanh(acc[l][0][r])*w0 + ftanh(acc[l][1][r])*w1;
  }
  #pragma unroll
  for (int l=0;l<3;l++)
    #pragma unroll
    for (int r=0;r<4;r++){
      float s = sc[l][r];
      s += __shfl_xor(s, 1);
      s += __shfl_xor(s, 2);
      s += __shfl_xor(s, 4);
      s += __shfl_xor(s, 8);
      sc[l][r] = s;
    }

  float lam[3][4];
  #pragma unroll
  for (int r=0;r<4;r++){
    float m = fmaxf(sc[0][r], fmaxf(sc[1][r], sc[2][r]));
    float e0 = __expf(sc[0][r]-m), e1 = __expf(sc[1][r]-m), e2 = __expf(sc[2][r]-m);
    float inv = 1.f/(e0+e1+e2);
    lam[0][r]=e0*inv; lam[1][r]=e1*inv; lam[2][r]=e2*inv;
  }
  int rsel = rA & 3;
  int srcLane = ((rA>>2)<<4) | rA;
  float p0 = rsel==0 ? lam[0][0] : rsel==1 ? lam[0][1] : rsel==2 ? lam[0][2] : lam[0][3];
  float p1 = rsel==0 ? lam[1][0] : rsel==1 ? lam[1][1] : rsel==2 ? lam[1][2] : lam[1][3];
  float p2 = rsel==0 ? lam[2][0] : rsel==1 ? lam[2][1] : rsel==2 ? lam[2][2] : lam[2][3];
  float lamA[3];
  lamA[0] = __shfl(p0, srcLane);
  lamA[1] = __shfl(p1, srcLane);
  lamA[2] = __shfl(p2, srcLane);

  f32x4 oacc[3];
  #pragma unroll
  for (int nf=0;nf<3;nf++) oacc[nf] = (f32x4){0.f,0.f,0.f,0.f};
  #pragma unroll
  for (int ks=0;ks<4;ks++){
    int ko = ks*32 + g*8;
    bf16x8 asc[3];
    #pragma unroll
    for (int l=0;l<3;l++){
      #pragma unroll
      for (int i=0;i<8;i++) asc[l][i] = (short)f2bf(bfs(a[l][ks][i]) * lamA[l]);
    }
    #pragma unroll
    for (int nf=0;nf<3;nf++){
      bf16x8 bh = *reinterpret_cast<const bf16x8*>(WoutT + (size_t)(nf*16+rA)*128 + ko);
      bf16x8 bl = *reinterpret_cast<const bf16x8*>(WoutT + 6144 + (size_t)(nf*16+rA)*128 + ko);
      #pragma unroll
      for (int l=0;l<3;l++){
        oacc[nf] = __builtin_amdgcn_mfma_f32_16x16x32_bf16(asc[l], bh, oacc[nf], 0, 0, 0);
        oacc[nf] = __builtin_amdgcn_mfma_f32_16x16x32_bf16(asc[l], bl, oacc[nf], 0, 0, 0);
      }
    }
  }

  #pragma unroll
  for (int nf=0;nf<3;nf++){
    int col = nf*16 + rA;
    float bv = (col < 40) ? bout[col] : 0.f;
    #pragma unroll
    for (int r=0;r<4;r++){
      int row = r0 + g*4 + r;
      if (row < M && col < 40) out[(size_t)row*40 + col] = oacc[nf][r] + bv;
    }
  }
}

extern "C" void kernel_launch(void* const* d_in, const int* in_sizes, int n_in,
                              void* d_out, int out_size, void* d_ws, size_t ws_size,
                              hipStream_t stream)
{
  const float* x    = (const float*)d_in[0];
  const int*   ei   = (const int*)d_in[1];
  const float* W0   = (const float*)d_in[2];
  const float* as0  = (const float*)d_in[3];
  const float* ad0  = (const float*)d_in[4];
  const float* b0   = (const float*)d_in[5];
  const float* W12  = (const float*)d_in[6];
  const float* as12 = (const float*)d_in[7];
  const float* ad12 = (const float*)d_in[8];
  const float* b12  = (const float*)d_in[9];
  const float* Watt = (const float*)d_in[10];
  const float* aatt = (const float*)d_in[11];
  const float* Wout = (const float*)d_in[12];
  const float* bout = (const float*)d_in[13];
  const int N_ = in_sizes[0] / 128;
  const int E_ = in_sizes[1] / 2;
  const int Et = E_ + N_;
  const int nb = (N_ + 1023) >> 10;

  char* p = (char*)d_ws;
  auto carve = [&](size_t bytes)->char*{ char* r = p; p += (bytes + 255) & ~(size_t)255; return r; };
  unsigned short* htmpA = (unsigned short*)carve((size_t)N_*128*2);
  unsigned short* htmpB = (unsigned short*)carve((size_t)N_*128*2);
  unsigned short* h0   = (unsigned short*)carve((size_t)N_*128*2);
  unsigned short* h1   = (unsigned short*)carve((size_t)N_*128*2);
  unsigned short* h2   = (unsigned short*)carve((size_t)N_*128*2);
  unsigned short* wsT  = (unsigned short*)carve((size_t)(5*18432 + 48*128)*2);
  float* ssrcA  = (float*)carve((size_t)N_*8*4);
  float* sdstA  = (float*)carve((size_t)N_*8*4);
  float* ssrcB  = (float*)carve((size_t)N_*8*4);
  float* sdstB  = (float*)carve((size_t)N_*8*4);
  int* offv      = (int*)carve((size_t)(N_+1)*4);
  int* bcnt      = (int*)carve((size_t)64*4);
  unsigned* bdata= (unsigned*)carve((size_t)64*BCAP*4);
  int* csr       = (int*)carve((size_t)(Et+8)*4);

  hipMemsetAsync(bcnt, 0, 64*4, stream);
  int gB = (Et + 2047)/2048;
  int gM = (N_+127)/128;
  k_prep_bucket<<<5+gB,256,0,stream>>>(W0, W12, Watt, as0, ad0, as12, ad12, Wout, wsT,
                                       ei, bcnt, bdata, E_, Et);
  k_bfinish_gemm0<<<nb+gM,512,0,stream>>>(bdata, bcnt, offv, csr, N_, nb,
                                          x, wsT, htmpA, ssrcA, sdstA);

  int gN8 = (N_+7)/8;
  int gF  = (N_+63)/64;
  // layer 0 aggregate + fused layer-1 GEMM (A buffers -> B buffers)
  k_agg_gemm<1><<<gN8,256,0,stream>>>(offv, csr, htmpA, ssrcA, sdstA, b0, h0, N_,
                                      wsT + (size_t)1*18432, htmpB, ssrcB, sdstB);
  // layer 1 aggregate + fused layer-2 GEMM (B buffers -> A buffers)
  k_agg_gemm<1><<<gN8,256,0,stream>>>(offv, csr, htmpB, ssrcB, sdstB, b12, h1, N_,
                                      wsT + (size_t)2*18432, htmpA, ssrcA, sdstA);
  // layer 2 aggregate (no fuse)
  k_agg_gemm<0><<<gN8,256,0,stream>>>(offv, csr, htmpA, ssrcA, sdstA, b12 + 128, h2, N_,
                                      nullptr, nullptr, nullptr, nullptr);
  k_final4<<<gF,256,0,stream>>>(h0, h1, h2, wsT + (size_t)3*18432, aatt,
                                wsT + (size_t)4*18432, bout, (float*)d_out, N_);
}